// Round 4
// baseline (188.111 us; speedup 1.0000x reference)
//
#include <hip/hip_runtime.h>

typedef unsigned int u32;
typedef unsigned short u16;
typedef __attribute__((ext_vector_type(4))) float fx4;
typedef __attribute__((ext_vector_type(8))) short s16x8;
typedef __attribute__((ext_vector_type(4))) u32 u32x4;

#define DD 128
#define KK 1024

__device__ __forceinline__ u16 f2bf(float f) {
  u32 u = __float_as_uint(f);
  return (u16)((u + 0x7FFFu + ((u >> 16) & 1u)) >> 16);
}
__device__ __forceinline__ u32 umin32(u32 a, u32 b) { return a < b ? a : b; }

typedef __attribute__((address_space(1))) const unsigned char ga_byte;
typedef __attribute__((address_space(3))) unsigned char ls_byte;
__device__ __forceinline__ void gl_lds16(const void* g, void* l) {
  __builtin_amdgcn_global_load_lds((ga_byte*)g, (ls_byte*)l, 16, 0, 0);
}

// ---------------- prep: cb fp32 -> bf16 (RTN, bit-identical to prior rounds),
// transposed to slab order cbw: [slab(64)][ku(16)][col(64)][8] u16, slab = lvl*16+cidx.
// Reads: 8 KB contiguous per wave. Writes: 256 B contiguous segments (4/instr).
// Also zeroes the loss slot in d_out. 64 blocks x 256 thr.
extern "C" __global__ __launch_bounds__(256) void rvq_prep(
    const float* __restrict__ cbf, u16* __restrict__ cbw,
    float* __restrict__ lossout) {
  if (blockIdx.x == 0 && threadIdx.x == 0) lossout[0] = 0.f;
  const int col = threadIdx.x >> 2, dq = threadIdx.x & 3;
  const float* src = cbf + ((size_t)blockIdx.x * 64 + col) * DD + dq * 32;
  u32* dst = (u32*)cbw + (size_t)blockIdx.x * 4096;
#pragma unroll
  for (int k8 = 0; k8 < 4; ++k8) {
    const fx4 a = *(const fx4*)(src + k8 * 8);
    const fx4 b = *(const fx4*)(src + k8 * 8 + 4);
    u32x4 pk;
    pk.x = (u32)f2bf(a[0]) | ((u32)f2bf(a[1]) << 16);
    pk.y = (u32)f2bf(a[2]) | ((u32)f2bf(a[3]) << 16);
    pk.z = (u32)f2bf(b[0]) | ((u32)f2bf(b[1]) << 16);
    pk.w = (u32)f2bf(b[2]) | ((u32)f2bf(b[3]) << 16);
    *(u32x4*)(dst + ((size_t)(dq * 4 + k8) * 64 + col) * 4) = pk;
  }
}

// ---------------- main: 512 blocks x 512 thr; block = 64 rows x 1024 cols.
// 8 waves = pair(2 row-halves of 32) x hq(4 col-16-slices per 64-col slab).
// Slab = 64 cols (16 KB bf16), double-buffered gl_lds, rotated visit order.
// fp32 residual in Rlds; epilogue: all waves redundantly rebuild afr from
// (old Rlds + winner codeword); one barrier; hq0 recomputes and writes back.
extern "C" __global__ __launch_bounds__(512, 2) void rvq_main(
    const float* __restrict__ x, const float* __restrict__ cbf,
    const u16* __restrict__ cbw, float* __restrict__ yout,
    float* __restrict__ lossacc) {
  __shared__ u16 bufs[2][16][64][8];   // 2 x 16 KB, k-major [buf][ku][col][8]
  __shared__ float Rlds[64][132];      // negated residual; +4 pad -> 2-way (free)
  __shared__ u32 lmin[2][32][4];       // [pair][row][hq]

  const int tid = threadIdx.x;
  const int w = tid >> 6, lane = tid & 63;
  const int c = lane & 15, q = lane >> 4;
  const int hq = w & 3, pair = w >> 2;
  const int rowbase = blockIdx.x * 64 + pair * 32;
  const int rot = (blockIdx.x >> 3) & 15;  // de-lockstep same-XCD L2 streams

  const u32 soff = (u32)(w * 2048 + lane * 16);
  const char* gcb = (const char*)cbw;
  char* lb0 = (char*)&bufs[0][0][0][0];
  const u32 boff = (u32)(q * 1024 + (hq * 16 + c) * 16);
  const u32 Kbase = (u32)(hq * 16 + c) - 0x80000000u;  // key = (bits<<10)+Kbase+cidx*64

  { // prologue: stage slab (lvl0, cidx=rot) into buf0
    const char* g = gcb + rot * 16384 + soff;
    gl_lds16(g, lb0 + soff);
    gl_lds16(g + 1024, lb0 + soff + 1024);
  }

  s16x8 afr[2][4];  // bf16 A-frags of negated residual (32 rows x 128 k)
#pragma unroll
  for (int t2 = 0; t2 < 2; ++t2) {
    const int row = pair * 32 + t2 * 16 + c;
    const float* xr = x + (size_t)(rowbase + t2 * 16 + c) * DD + q * 8;
#pragma unroll
    for (int s = 0; s < 4; ++s) {
      const fx4 a = *(const fx4*)(xr + s * 32);
      const fx4 b = *(const fx4*)(xr + s * 32 + 4);
      fx4 na, nb;
      s16x8 af;
#pragma unroll
      for (int j = 0; j < 4; ++j) { na[j] = -a[j]; nb[j] = -b[j]; }
#pragma unroll
      for (int j = 0; j < 4; ++j) { af[j] = (short)f2bf(na[j]); af[4 + j] = (short)f2bf(nb[j]); }
      afr[t2][s] = af;
      if (hq == 0) {
        *(fx4*)&Rlds[row][s * 32 + q * 8] = na;
        *(fx4*)&Rlds[row][s * 32 + q * 8 + 4] = nb;
      }
    }
  }

  u32 run[2][4];
#pragma unroll
  for (int t2 = 0; t2 < 2; ++t2)
#pragma unroll
    for (int r = 0; r < 4; ++r) run[t2][r] = 0xFFFFFFFFu;

  float lsum = 0.f;

#pragma unroll 1
  for (int it = 0; it < 64; ++it) {
    const int buf = it & 1;
    const int cidx = ((it & 15) + rot) & 15;
    __syncthreads();  // buf staged (drains gl_lds); prev lmin/Rlds writes visible

    if (it + 1 < 64) {  // prefetch next slab into other buffer (issue early)
      const int nl = (it + 1) >> 4;
      const int nc = (((it + 1) & 15) + rot) & 15;
      const char* g = gcb + (size_t)((nl * 16 + nc) * 16384) + soff;
      char* l = lb0 + ((it + 1) & 1) * 16384 + soff;
      gl_lds16(g, l);
      gl_lds16(g + 1024, l + 1024);
    }

    if ((it & 15) == 0 && it > 0) {  // ---- epilogue for previous level
      const int plvl = (it >> 4) - 1;
#pragma unroll
      for (int t2 = 0; t2 < 2; ++t2) {
        const int row = pair * 32 + t2 * 16 + c;
        const u32x4 p = *(const u32x4*)&lmin[pair][t2 * 16 + c][0];
        const u32 pm = umin32(umin32(p.x, p.y), umin32(p.z, p.w));
        const int col = (int)(pm & 1023u);
        const float* qp = cbf + ((size_t)(plvl * KK + col)) * DD + q * 8;
#pragma unroll
        for (int s = 0; s < 4; ++s) {
          fx4 r0 = *(const fx4*)&Rlds[row][s * 32 + q * 8];
          fx4 r1 = *(const fx4*)&Rlds[row][s * 32 + q * 8 + 4];
          const fx4 qa = *(const fx4*)(qp + s * 32);
          const fx4 qb = *(const fx4*)(qp + s * 32 + 4);
          s16x8 af;
#pragma unroll
          for (int j = 0; j < 4; ++j) { r0[j] += qa[j]; r1[j] += qb[j]; }
#pragma unroll
          for (int j = 0; j < 4; ++j) { af[j] = (short)f2bf(r0[j]); af[4 + j] = (short)f2bf(r1[j]); }
          afr[t2][s] = af;
        }
      }
      __syncthreads();  // all old-Rlds reads done before hq0 writes new values
      if (hq == 0) {    // recompute (cheap, L1-hot) and commit; no held registers
#pragma unroll
        for (int t2 = 0; t2 < 2; ++t2) {
          const int row = pair * 32 + t2 * 16 + c;
          const u32x4 p = *(const u32x4*)&lmin[pair][t2 * 16 + c][0];
          const u32 pm = umin32(umin32(p.x, p.y), umin32(p.z, p.w));
          const int col = (int)(pm & 1023u);
          const float* qp = cbf + ((size_t)(plvl * KK + col)) * DD + q * 8;
#pragma unroll
          for (int s = 0; s < 4; ++s) {
            fx4 r0 = *(const fx4*)&Rlds[row][s * 32 + q * 8];
            fx4 r1 = *(const fx4*)&Rlds[row][s * 32 + q * 8 + 4];
            const fx4 qa = *(const fx4*)(qp + s * 32);
            const fx4 qb = *(const fx4*)(qp + s * 32 + 4);
#pragma unroll
            for (int j = 0; j < 4; ++j) {
              r0[j] += qa[j]; r1[j] += qb[j];
              lsum = fmaf(r0[j], r0[j], lsum);
              lsum = fmaf(r1[j], r1[j], lsum);
            }
            *(fx4*)&Rlds[row][s * 32 + q * 8] = r0;
            *(fx4*)&Rlds[row][s * 32 + q * 8 + 4] = r1;
          }
        }
      }
#pragma unroll
      for (int t2 = 0; t2 < 2; ++t2)
#pragma unroll
        for (int r = 0; r < 4; ++r) run[t2][r] = 0xFFFFFFFFu;
    }

    // ---- compute this slab
    const char* bb = lb0 + buf * 16384 + boff;
    const u32 kadd = Kbase + (u32)(cidx * 64);
    fx4 a0 = {0.75f, 0.75f, 0.75f, 0.75f};  // acc = 0.75 - r.c
    fx4 a1 = a0;
#pragma unroll
    for (int s = 0; s < 4; ++s) {
      const s16x8 bf = *(const s16x8*)(bb + s * 4096);
      a0 = __builtin_amdgcn_mfma_f32_16x16x32_bf16(afr[0][s], bf, a0, 0, 0, 0);
      a1 = __builtin_amdgcn_mfma_f32_16x16x32_bf16(afr[1][s], bf, a1, 0, 0, 0);
    }
#pragma unroll
    for (int r = 0; r < 4; ++r) {
      run[0][r] = umin32(run[0][r], (__float_as_uint(a0[r]) << 10) + kadd);
      run[1][r] = umin32(run[1][r], (__float_as_uint(a1[r]) << 10) + kadd);
    }

    if ((it & 15) == 15) {  // level done: reduce + publish per-wave minima
#pragma unroll
      for (int m = 1; m < 16; m <<= 1)
#pragma unroll
        for (int t2 = 0; t2 < 2; ++t2)
#pragma unroll
          for (int r = 0; r < 4; ++r)
            run[t2][r] = umin32(run[t2][r], (u32)__shfl_xor((int)run[t2][r], m, 64));
      if (c == 0) {
#pragma unroll
        for (int t2 = 0; t2 < 2; ++t2)
#pragma unroll
          for (int r = 0; r < 4; ++r)
            lmin[pair][t2 * 16 + q * 4 + r][hq] = run[t2][r];
      }
    }
  }

  __syncthreads();  // final lmin visible
  if (hq == 0) {    // final level: y = x + newR; loss
#pragma unroll
    for (int t2 = 0; t2 < 2; ++t2) {
      const int row = pair * 32 + t2 * 16 + c;
      const u32x4 p = *(const u32x4*)&lmin[pair][t2 * 16 + c][0];
      const u32 pm = umin32(umin32(p.x, p.y), umin32(p.z, p.w));
      const int col = (int)(pm & 1023u);
      const float* qp = cbf + ((size_t)(3 * KK + col)) * DD + q * 8;
      const size_t base = (size_t)(rowbase + t2 * 16 + c) * DD + q * 8;
#pragma unroll
      for (int s = 0; s < 4; ++s) {
        fx4 r0 = *(const fx4*)&Rlds[row][s * 32 + q * 8];
        fx4 r1 = *(const fx4*)&Rlds[row][s * 32 + q * 8 + 4];
        const fx4 qa = *(const fx4*)(qp + s * 32);
        const fx4 qb = *(const fx4*)(qp + s * 32 + 4);
        const fx4 xa = *(const fx4*)(x + base + s * 32);
        const fx4 xb = *(const fx4*)(x + base + s * 32 + 4);
        fx4 ya, yb;
#pragma unroll
        for (int j = 0; j < 4; ++j) {
          r0[j] += qa[j]; r1[j] += qb[j];
          lsum = fmaf(r0[j], r0[j], lsum);
          lsum = fmaf(r1[j], r1[j], lsum);
          ya[j] = xa[j] + r0[j]; yb[j] = xb[j] + r1[j];
        }
        *(fx4*)(yout + base + s * 32) = ya;
        *(fx4*)(yout + base + s * 32 + 4) = yb;
      }
    }
#pragma unroll
    for (int m = 32; m >= 1; m >>= 1) lsum += __shfl_xor(lsum, m, 64);
    if (lane == 0) atomicAdd(lossacc, lsum * (1.25f / 4194304.f));  // 1.25/(N*D)
  }
}

extern "C" void kernel_launch(void* const* d_in, const int* in_sizes, int n_in,
                              void* d_out, int out_size, void* d_ws, size_t ws_size,
                              hipStream_t stream) {
  const float* x = (const float*)d_in[0];     // [32768,128]
  const float* cbf = (const float*)d_in[1];   // [4,1024,128]
  float* y = (float*)d_out;
  float* lossout = y + (out_size - 1);
  u16* cbw = (u16*)d_ws;                      // 1 MiB transposed bf16 codebook

  rvq_prep<<<64, 256, 0, stream>>>(cbf, cbw, lossout);
  rvq_main<<<512, 512, 0, stream>>>(x, cbf, cbw, y, lossout);
}

// Round 5
// 146.027 us; speedup vs baseline: 1.2882x; 1.2882x over previous
//
#include <hip/hip_runtime.h>

typedef unsigned int u32;
typedef unsigned short u16;
typedef __attribute__((ext_vector_type(4))) float fx4;
typedef __attribute__((ext_vector_type(8))) short s16x8;
typedef __attribute__((ext_vector_type(4))) u32 u32x4;

#define DD 128
#define KK 1024

__device__ __forceinline__ u16 f2bf(float f) {
  u32 u = __float_as_uint(f);
  return (u16)((u + 0x7FFFu + ((u >> 16) & 1u)) >> 16);
}
__device__ __forceinline__ u32 umin32(u32 a, u32 b) { return a < b ? a : b; }

// ---------------- prep: cbf fp32 -> bf16 (RTN, bit-identical to prior rounds),
// k-major cbt: [lvl(4)][ku(16)][col(1024)][8] u16 (1 MiB). 256 blocks x 64 thr,
// block = 16 codewords. Also zeroes the loss slot in d_out.
extern "C" __global__ __launch_bounds__(64) void rvq_prep(
    const float* __restrict__ cbf, u16* __restrict__ cbt,
    float* __restrict__ lossout) {
  if (blockIdx.x == 0 && threadIdx.x == 0) lossout[0] = 0.f;
  const int cl = threadIdx.x >> 2, dq = threadIdx.x & 3;
  const int cw = blockIdx.x * 16 + cl;
  const int lvl = cw >> 10, colg = cw & 1023;
  const float* src = cbf + (size_t)cw * DD + dq * 32;
  u32x4* dst = (u32x4*)cbt;
#pragma unroll
  for (int k8 = 0; k8 < 4; ++k8) {
    const fx4 a = *(const fx4*)(src + k8 * 8);
    const fx4 b = *(const fx4*)(src + k8 * 8 + 4);
    u32x4 pk;
    pk.x = (u32)f2bf(a[0]) | ((u32)f2bf(a[1]) << 16);
    pk.y = (u32)f2bf(a[2]) | ((u32)f2bf(a[3]) << 16);
    pk.z = (u32)f2bf(b[0]) | ((u32)f2bf(b[1]) << 16);
    pk.w = (u32)f2bf(b[2]) | ((u32)f2bf(b[3]) << 16);
    dst[((lvl * 16 + dq * 4 + k8) * 1024) + colg] = pk;  // 1 KB-coalesced across block
  }
}

// ---------------- main: 512 blocks x 256 thr; block = 64 rows x 1024 cols.
// 4 waves; EACH wave holds all 64 rows as A-frags (afr[4][4]) and scans a
// 16-col slice per tile (wave wv covers cols {tile*64 + wv*16 + c}).
// B-frags stream straight from L2 (global_load_dwordx4, quarter-wave-contiguous),
// hand double-buffered — NO LDS staging, NO barriers in the K-loop.
// Per level only: lmin exchange (1 barrier) + Rlds update/rebuild (1 barrier).
extern "C" __global__ __launch_bounds__(256, 2) void rvq_main(
    const float* __restrict__ x, const float* __restrict__ cbf,
    const u16* __restrict__ cbt, float* __restrict__ yout,
    float* __restrict__ lossacc) {
  __shared__ float Rlds[64][132];  // negated residual, single copy; +4 pad
  __shared__ u32 lmin[64][4];      // [row][wave]

  const int tid = threadIdx.x;
  const int wv = tid >> 6, lane = tid & 63;
  const int c = lane & 15, q = lane >> 4;
  const int rowbase = blockIdx.x * 64;
  const int rot = (int)((blockIdx.x >> 3) & 15);  // de-lockstep same-XCD L2 streams
  const s16x8* cbt16 = (const s16x8*)cbt;         // 16B units: [lvl][ku][col]

  s16x8 afr[4][4];  // A-frags: afr[t][s] -> rows t*16+c, k = s*32 + q*8 + j
#pragma unroll
  for (int t = 0; t < 4; ++t) {
    const float* xr = x + (size_t)(rowbase + t * 16 + c) * DD + q * 8;
#pragma unroll
    for (int s = 0; s < 4; ++s) {
      const fx4 a = *(const fx4*)(xr + s * 32);
      const fx4 b = *(const fx4*)(xr + s * 32 + 4);
      fx4 na, nb;
      s16x8 af;
#pragma unroll
      for (int j = 0; j < 4; ++j) { na[j] = -a[j]; nb[j] = -b[j]; }
#pragma unroll
      for (int j = 0; j < 4; ++j) { af[j] = (short)f2bf(na[j]); af[4 + j] = (short)f2bf(nb[j]); }
      afr[t][s] = af;
      if (t == wv) {  // wave wv owns Rlds rows wv*16..wv*16+15
        *(fx4*)&Rlds[t * 16 + c][s * 32 + q * 8] = na;
        *(fx4*)&Rlds[t * 16 + c][s * 32 + q * 8 + 4] = nb;
      }
    }
  }

  u32 run[4][4];
#pragma unroll
  for (int t = 0; t < 4; ++t)
#pragma unroll
    for (int r = 0; r < 4; ++r) run[t][r] = 0xFFFFFFFFu;

  float lsum = 0.f;

#pragma unroll 1
  for (int lvl = 0; lvl < 4; ++lvl) {
    const s16x8* cl = cbt16 + lvl * 16384 + q * 1024 + c;  // + s*4096 + colbase
    s16x8 brA[4], brB[4];
    {
      const int cb0 = rot * 64 + wv * 16;
#pragma unroll
      for (int s5 = 0; s5 < 4; ++s5) brA[s5] = cl[s5 * 4096 + cb0];
    }
    // acc = 0.75 - r.c  in (0.625, 0.875) [|r.c| <= ~0.04 here, wrap-safe to 0.125]
    // key = (bits(acc)<<10) + col - 2^31 : monotone, ties -> lowest col.
#define KSTEP(CUR, NXT, CT)                                                        \
  {                                                                                \
    if ((CT) < 15) {                                                               \
      const int cbn = ((((CT) + 1 + rot) & 15) * 64) + wv * 16;                    \
      _Pragma("unroll") for (int s5 = 0; s5 < 4; ++s5)                             \
          NXT[s5] = cl[s5 * 4096 + cbn];                                           \
    }                                                                              \
    const u32 kadd = (u32)(((((CT) + rot) & 15) * 64) + wv * 16 + c) - 0x80000000u;\
    fx4 ac0 = {0.75f, 0.75f, 0.75f, 0.75f};                                        \
    fx4 ac1 = ac0, ac2 = ac0, ac3 = ac0;                                           \
    _Pragma("unroll") for (int s5 = 0; s5 < 4; ++s5) {                             \
      const s16x8 bfrag = CUR[s5];                                                 \
      ac0 = __builtin_amdgcn_mfma_f32_16x16x32_bf16(afr[0][s5], bfrag, ac0, 0, 0, 0); \
      ac1 = __builtin_amdgcn_mfma_f32_16x16x32_bf16(afr[1][s5], bfrag, ac1, 0, 0, 0); \
      ac2 = __builtin_amdgcn_mfma_f32_16x16x32_bf16(afr[2][s5], bfrag, ac2, 0, 0, 0); \
      ac3 = __builtin_amdgcn_mfma_f32_16x16x32_bf16(afr[3][s5], bfrag, ac3, 0, 0, 0); \
    }                                                                              \
    _Pragma("unroll") for (int r5 = 0; r5 < 4; ++r5) {                             \
      run[0][r5] = umin32(run[0][r5], (__float_as_uint(ac0[r5]) << 10) + kadd);    \
      run[1][r5] = umin32(run[1][r5], (__float_as_uint(ac1[r5]) << 10) + kadd);    \
      run[2][r5] = umin32(run[2][r5], (__float_as_uint(ac2[r5]) << 10) + kadd);    \
      run[3][r5] = umin32(run[3][r5], (__float_as_uint(ac3[r5]) << 10) + kadd);    \
    }                                                                              \
  }
    KSTEP(brA, brB, 0)  KSTEP(brB, brA, 1)  KSTEP(brA, brB, 2)  KSTEP(brB, brA, 3)
    KSTEP(brA, brB, 4)  KSTEP(brB, brA, 5)  KSTEP(brA, brB, 6)  KSTEP(brB, brA, 7)
    KSTEP(brA, brB, 8)  KSTEP(brB, brA, 9)  KSTEP(brA, brB, 10) KSTEP(brB, brA, 11)
    KSTEP(brA, brB, 12) KSTEP(brB, brA, 13) KSTEP(brA, brB, 14) KSTEP(brB, brA, 15)
#undef KSTEP

    // reduce over the 16 c-lanes (row lives on q*4+r within tile t)
#pragma unroll
    for (int m = 1; m < 16; m <<= 1)
#pragma unroll
      for (int t = 0; t < 4; ++t)
#pragma unroll
        for (int r = 0; r < 4; ++r)
          run[t][r] = umin32(run[t][r], (u32)__shfl_xor((int)run[t][r], m, 64));
    if (c == 0) {
#pragma unroll
      for (int t = 0; t < 4; ++t)
#pragma unroll
        for (int r = 0; r < 4; ++r)
          lmin[t * 16 + q * 4 + r][wv] = run[t][r];
    }
    __syncthreads();  // lmin complete across the 4 waves

    // update own rows: row = wv*16 + c, dims q*32..q*32+31 (exact fp32 codebook)
    const int row = wv * 16 + c;
    const u32x4 p = *(const u32x4*)&lmin[row][0];
    const u32 pm = umin32(umin32(p.x, p.y), umin32(p.z, p.w));
    const int col = (int)(pm & 1023u);
    const float* qp = cbf + ((size_t)lvl * KK + col) * DD + q * 32;
    float* Rr = &Rlds[row][q * 32];
    if (lvl < 3) {
#pragma unroll
      for (int k4 = 0; k4 < 8; ++k4) {
        fx4 rv = *(const fx4*)(Rr + k4 * 4);
        const fx4 qv = *(const fx4*)(qp + k4 * 4);
#pragma unroll
        for (int j = 0; j < 4; ++j) { rv[j] += qv[j]; lsum = fmaf(rv[j], rv[j], lsum); }
        *(fx4*)(Rr + k4 * 4) = rv;
      }
      __syncthreads();  // new residual visible; also orders lmin reads vs next level
      // rebuild all 64 rows' A-frags from Rlds; reset keys
#pragma unroll
      for (int t = 0; t < 4; ++t)
#pragma unroll
        for (int s = 0; s < 4; ++s) {
          const fx4 r0 = *(const fx4*)&Rlds[t * 16 + c][s * 32 + q * 8];
          const fx4 r1 = *(const fx4*)&Rlds[t * 16 + c][s * 32 + q * 8 + 4];
          s16x8 af;
#pragma unroll
          for (int j = 0; j < 4; ++j) { af[j] = (short)f2bf(r0[j]); af[4 + j] = (short)f2bf(r1[j]); }
          afr[t][s] = af;
        }
#pragma unroll
      for (int t = 0; t < 4; ++t)
#pragma unroll
        for (int r = 0; r < 4; ++r) run[t][r] = 0xFFFFFFFFu;
    } else {  // final level: y = x + R_final (forward value = q_sum)
      const size_t gb = (size_t)(rowbase + row) * DD + q * 32;
#pragma unroll
      for (int k4 = 0; k4 < 8; ++k4) {
        fx4 rv = *(const fx4*)(Rr + k4 * 4);
        const fx4 qv = *(const fx4*)(qp + k4 * 4);
        const fx4 xv = *(const fx4*)(x + gb + k4 * 4);
        fx4 yv;
#pragma unroll
        for (int j = 0; j < 4; ++j) {
          rv[j] += qv[j];
          lsum = fmaf(rv[j], rv[j], lsum);
          yv[j] = xv[j] + rv[j];
        }
        *(fx4*)(yout + gb + k4 * 4) = yv;
      }
    }
  }

#pragma unroll
  for (int m = 32; m >= 1; m >>= 1) lsum += __shfl_xor(lsum, m, 64);
  if (lane == 0) atomicAdd(lossacc, lsum * (1.25f / 4194304.f));  // 1.25/(N*D)
}

extern "C" void kernel_launch(void* const* d_in, const int* in_sizes, int n_in,
                              void* d_out, int out_size, void* d_ws, size_t ws_size,
                              hipStream_t stream) {
  const float* x = (const float*)d_in[0];     // [32768,128]
  const float* cbf = (const float*)d_in[1];   // [4,1024,128]
  float* y = (float*)d_out;
  float* lossout = y + (out_size - 1);
  u16* cbt = (u16*)d_ws;                      // 1 MiB k-major bf16 codebook

  rvq_prep<<<256, 64, 0, stream>>>(cbf, cbt, lossout);
  rvq_main<<<512, 256, 0, stream>>>(x, cbf, cbt, y, lossout);
}